// Round 3
// baseline (450.717 us; speedup 1.0000x reference)
//
#include <hip/hip_runtime.h>
#include <stdint.h>

// ExactTopKAttention: B=1, T=S=2048, H=16, E=64, topk=32, fp32.
//   - block = (head h, 16 t-rows), 256 threads = 4 waves, wave owns 4 rows
//   - QK^T GEMM fp32: K staged in LDS (512s x 16e swizzled), Q wave-uniform
//     loads; scores are a SEQUENTIAL fp32 FMA chain over e=0..63 (bit-
//     identical to BLAS/Eigen microkernels -> matches the np/jax reference's
//     fp32 rounding at the top-k boundary; final *0.125f commutes exactly)
//   - exact top-32 on those fp32 scores: adaptive 10-bit radix refinement
//     (overflow-proof, <=64 candidates guaranteed) -> 64-wide bitonic on
//     ((ord32<<32)|~idx)  (value desc, index asc = lax.top_k tie order)
//   - softmax over the 32 survivors (same fp32 scores), V gather, store.

#define T_DIM 2048
#define S_DIM 2048
#define H_DIM 16
#define E_DIM 64
#define K_TOP 32
#define TT 16        // t rows per block
#define SCHUNK 512   // s rows per chunk
#define ESLICE 16    // e per LDS slice

// order-preserving float->uint map (monotone increasing)
__device__ __forceinline__ unsigned f2ord(float f) {
    unsigned b = __float_as_uint(f);
    return (b & 0x80000000u) ? ~b : (b | 0x80000000u);
}
__device__ __forceinline__ float ord2f(unsigned u) {
    unsigned b = (u & 0x80000000u) ? (u ^ 0x80000000u) : ~u;
    return __uint_as_float(b);
}
// histogram bank remap: bin b -> ((b&15)<<6)|(b>>4); lane L's descending
// 16-bin segment maps to consecutive banks (conflict-free scan).
__device__ __forceinline__ int hmap(int b) { return ((b & 15) << 6) | (b >> 4); }

__global__ __launch_bounds__(256, 2)
void topk_attn_kernel(const float* __restrict__ Qg,
                      const float* __restrict__ Kg,
                      const float* __restrict__ Vg,
                      float* __restrict__ Out) {
    __shared__ float    sK[SCHUNK * ESLICE];   // 32 KB, swizzled float4 slots
    __shared__ unsigned hist[4][1024];         // 16 KB, per-wave
    __shared__ unsigned candU[4][64];
    __shared__ int      candI[4][64];
    __shared__ unsigned wcnt[4];

    const int tid  = threadIdx.x;
    const int lane = tid & 63;
    const int wv   = tid >> 6;                 // wave 0..3
    const int bx   = blockIdx.x;
    const int h    = bx & (H_DIM - 1);         // consecutive bx -> same XCD per head
    const int tb   = bx >> 4;
    const int t0   = tb * TT + wv * 4;         // this wave's first t row

    // acc[jj][chunk][i]: score(t0+jj, s = chunk*512 + 64*i + lane), pre-scale
    float acc[4][4][8];
    #pragma unroll
    for (int a = 0; a < 4; a++)
        #pragma unroll
        for (int b = 0; b < 4; b++)
            #pragma unroll
            for (int c = 0; c < 8; c++) acc[a][b][c] = 0.f;

    const int swz = (lane >> 1) & 3;           // == ((s>>1)&3) for s = lane + 64*i

    #pragma unroll
    for (int ch = 0; ch < 4; ch++) {           // s chunks of 512
        for (int es = 0; es < 4; es++) {       // e slices of 16
            __syncthreads();
            // stage K[ch*512 .. +512)[es*16 .. +16) -> sK
            #pragma unroll
            for (int r = 0; r < 8; r++) {
                int p   = tid + 256 * r;       // float4 piece id, 2048 total
                int sl  = p >> 2;
                int col = p & 3;
                const float4 kv = *(const float4*)(Kg +
                    ((size_t)(ch * SCHUNK + sl) * H_DIM + h) * E_DIM
                    + es * ESLICE + col * 4);
                int slot = sl * 4 + ((col + ((sl >> 1) & 3)) & 3);  // XOR swizzle
                *(float4*)(sK + slot * 4) = kv;
            }
            __syncthreads();
            #pragma unroll
            for (int e4 = 0; e4 < 4; e4++) {
                float4 qf[4];
                #pragma unroll
                for (int jj = 0; jj < 4; jj++) {
                    int t = t0 + jj;
                    qf[jj] = *(const float4*)(Qg +
                        ((size_t)t * H_DIM + h) * E_DIM + es * ESLICE + e4 * 4);
                }
                #pragma unroll
                for (int i = 0; i < 8; i++) {
                    int sl   = lane + 64 * i;
                    int slot = sl * 4 + ((e4 + swz) & 3);
                    float4 kf = *(const float4*)(sK + slot * 4);
                    // e-sequential FMA chain (order matters for bit-match!)
                    #pragma unroll
                    for (int jj = 0; jj < 4; jj++) {
                        acc[jj][ch][i] = fmaf(qf[jj].x, kf.x, acc[jj][ch][i]);
                        acc[jj][ch][i] = fmaf(qf[jj].y, kf.y, acc[jj][ch][i]);
                        acc[jj][ch][i] = fmaf(qf[jj].z, kf.z, acc[jj][ch][i]);
                        acc[jj][ch][i] = fmaf(qf[jj].w, kf.w, acc[jj][ch][i]);
                    }
                }
            }
        }
    }

    // ---- selection + softmax + output (wave-local; no cross-wave state) ----
    const float* Vb = Vg + (size_t)h * E_DIM;

    #pragma unroll
    for (int jj = 0; jj < 4; jj++) {
        // --- adaptive radix: find exact threshold with <=64 candidates ---
        unsigned prefix = 0, count_above = 0, cnt_eq = 0;
        bool done = false;
        #pragma unroll
        for (int lvl = 0; lvl < 3; lvl++) {
            if (!done) {                       // wave-uniform condition
                const int shift = 22 - 10 * lvl;
                #pragma unroll
                for (int z = 0; z < 16; z++) hist[wv][z * 64 + lane] = 0u;
                #pragma unroll
                for (int ch = 0; ch < 4; ch++)
                    #pragma unroll
                    for (int i = 0; i < 8; i++) {
                        unsigned u = f2ord(acc[jj][ch][i] * 0.125f);
                        bool part = (lvl == 0) ||
                                    ((u >> (shift + 10)) == (prefix >> (shift + 10)));
                        if (part)
                            atomicAdd(&hist[wv][hmap((int)((u >> shift) & 1023u))], 1u);
                    }
                const unsigned need = K_TOP - count_above;   // >=1, wave-uniform
                unsigned seg = 0;
                const int btop = 1023 - 16 * lane;           // descending segments
                #pragma unroll
                for (int k = 0; k < 16; k++) seg += hist[wv][hmap(btop - k)];
                unsigned inc = seg;
                #pragma unroll
                for (int d = 1; d < 64; d <<= 1) {
                    unsigned y = __shfl_up(inc, d);
                    if (lane >= d) inc += y;
                }
                unsigned pre = inc - seg;                    // count above my segment
                bool cross = (pre < need) && (pre + seg >= need);
                int bl = 0; unsigned cg = 0, ce = 0;
                if (cross) {
                    unsigned c = pre;
                    #pragma unroll
                    for (int k = 0; k < 16; k++) {
                        unsigned hb = hist[wv][hmap(btop - k)];
                        if (c < need && c + hb >= need) { bl = btop - k; cg = c; ce = hb; }
                        c += hb;
                    }
                }
                int src = __ffsll((unsigned long long)__ballot(cross)) - 1;
                bl = __shfl(bl, src);
                cg = __shfl(cg, src);
                ce = __shfl(ce, src);
                prefix |= ((unsigned)bl) << shift;
                count_above += cg;             // stays < 32
                cnt_eq = ce;
                done = (count_above + cnt_eq <= 60u) || (lvl == 2);
            }
        }

        // --- collect candidates with u >= prefix (exact; same bits as radix) ---
        if (lane == 0) wcnt[wv] = 0u;
        #pragma unroll
        for (int ch = 0; ch < 4; ch++)
            #pragma unroll
            for (int i = 0; i < 8; i++) {
                unsigned u = f2ord(acc[jj][ch][i] * 0.125f);
                if (u >= prefix) {
                    unsigned pos = atomicAdd(&wcnt[wv], 1u);
                    if (pos < 64u) {
                        candU[wv][pos] = u;
                        candI[wv][pos] = ch * SCHUNK + i * 64 + lane;
                    }
                }
            }
        unsigned n = wcnt[wv];                 // 32 <= n <= ~61 structurally
        if (n > 64u) n = 64u;

        // --- 64-wide bitonic, descending by (value, then lower index) ---
        unsigned long long key = 0ull;
        if ((unsigned)lane < n)
            key = (((unsigned long long)candU[wv][lane]) << 32)
                | (unsigned)(~candI[wv][lane]);
        #pragma unroll
        for (int k = 2; k <= 64; k <<= 1)
            #pragma unroll
            for (int j = k >> 1; j > 0; j >>= 1) {
                unsigned long long ok = __shfl_xor(key, j);
                bool takemax = ((lane & j) == 0) ^ ((lane & k) != 0);
                bool mineG   = key > ok;
                key = (takemax == mineG) ? key : ok;
            }

        // --- decode, softmax over lanes 0..31 (fp32 scores), V gather ---
        float val  = ord2f((unsigned)(key >> 32));
        int   sidx = (int)(~(unsigned)key);
        float m = __shfl(val, 0);              // lane 0 = max (n >= 32 always)
        float w = (lane < K_TOP) ? expf(val - m) : 0.f;
        float Z = w;
        #pragma unroll
        for (int d = 32; d > 0; d >>= 1) Z += __shfl_xor(Z, d);
        float p = w / Z;

        float o = 0.f;
        #pragma unroll
        for (int i2 = 0; i2 < K_TOP; i2++) {
            float pi = __shfl(p, i2);
            int   s2 = __shfl(sidx, i2);
            o = fmaf(pi, Vb[(size_t)s2 * (H_DIM * E_DIM) + lane], o);
        }
        int t = t0 + jj;
        Out[((size_t)t * H_DIM + h) * E_DIM + lane] = o;
    }
}

extern "C" void kernel_launch(void* const* d_in, const int* in_sizes, int n_in,
                              void* d_out, int out_size, void* d_ws, size_t ws_size,
                              hipStream_t stream) {
    const float* Q = (const float*)d_in[0];
    const float* K = (const float*)d_in[1];
    const float* V = (const float*)d_in[2];
    float* O = (float*)d_out;
    (void)in_sizes; (void)n_in; (void)out_size; (void)d_ws; (void)ws_size;
    dim3 grid((T_DIM / TT) * H_DIM);   // 2048 blocks
    dim3 block(256);
    topk_attn_kernel<<<grid, block, 0, stream>>>(Q, K, V, O);
}

// Round 4
// 435.374 us; speedup vs baseline: 1.0352x; 1.0352x over previous
//
#include <hip/hip_runtime.h>
#include <stdint.h>

// ExactTopKAttention: B=1, T=S=2048, H=16, E=64, topk=32, fp32.
//   - block = (head h, 16 t-rows), 256 threads = 4 waves, wave owns 4 rows
//   - QK^T GEMM fp32: K staged in LDS (512s x 16e swizzled), Q wave-uniform
//     loads; scores are a SEQUENTIAL fp32 FMA chain over e=0..63 (bit-
//     identical to BLAS/Eigen microkernels -> matches the np/jax reference's
//     fp32 rounding at the top-k boundary; final *0.125f commutes exactly)
//   - exact top-32 on those fp32 scores: adaptive 10-bit radix refinement
//     (overflow-proof, <=64 candidates guaranteed) -> 64-wide bitonic on
//     ((ord32<<32)|~idx)  (value desc, index asc = lax.top_k tie order)
//   - softmax over the 32 survivors (same fp32 scores), V gather, store.
//
// R4 change: selection scratch (hist/cand/wcnt, 18.5 KB) is UNIONED into the
// 32 KB sK region (dead after the GEMM; one barrier protects the alias).
// LDS 51712 -> 32768 B: occupancy 2 -> 4 blocks/CU (VGPR=128 allows 4 w/SIMD).

#define T_DIM 2048
#define S_DIM 2048
#define H_DIM 16
#define E_DIM 64
#define K_TOP 32
#define TT 16        // t rows per block
#define SCHUNK 512   // s rows per chunk
#define ESLICE 16    // e per LDS slice

// order-preserving float->uint map (monotone increasing)
__device__ __forceinline__ unsigned f2ord(float f) {
    unsigned b = __float_as_uint(f);
    return (b & 0x80000000u) ? ~b : (b | 0x80000000u);
}
__device__ __forceinline__ float ord2f(unsigned u) {
    unsigned b = (u & 0x80000000u) ? (u ^ 0x80000000u) : ~u;
    return __uint_as_float(b);
}
// histogram bank remap: bin b -> ((b&15)<<6)|(b>>4); lane L's descending
// 16-bin segment maps to consecutive banks (conflict-free scan).
__device__ __forceinline__ int hmap(int b) { return ((b & 15) << 6) | (b >> 4); }

__global__ __launch_bounds__(256, 2)
void topk_attn_kernel(const float* __restrict__ Qg,
                      const float* __restrict__ Kg,
                      const float* __restrict__ Vg,
                      float* __restrict__ Out) {
    // Single 32 KB region: K-tile during GEMM, selection scratch afterwards.
    __shared__ __align__(16) float sK[SCHUNK * ESLICE];   // 32768 B total LDS

    const int tid  = threadIdx.x;
    const int lane = tid & 63;
    const int wv   = tid >> 6;                 // wave 0..3
    const int bx   = blockIdx.x;
    const int h    = bx & (H_DIM - 1);         // consecutive bx -> same XCD per head
    const int tb   = bx >> 4;
    const int t0   = tb * TT + wv * 4;         // this wave's first t row

    // selection scratch aliased onto sK (valid only after the post-GEMM barrier)
    unsigned* histw  = ((unsigned*)sK) + wv * 1024;            // [0, 16K)
    unsigned* candUw = ((unsigned*)sK) + 4096 + wv * 64;       // [16K, 17K)
    int*      candIw = ((int*)sK)      + 4096 + 256 + wv * 64; // [17K, 18K)
    unsigned* wcntw  = ((unsigned*)sK) + 4096 + 512 + wv;      // [18K, +16B)

    // acc[jj][chunk][i]: score(t0+jj, s = chunk*512 + 64*i + lane), pre-scale
    float acc[4][4][8];
    #pragma unroll
    for (int a = 0; a < 4; a++)
        #pragma unroll
        for (int b = 0; b < 4; b++)
            #pragma unroll
            for (int c = 0; c < 8; c++) acc[a][b][c] = 0.f;

    const int swz = (lane >> 1) & 3;           // == ((s>>1)&3) for s = lane + 64*i

    #pragma unroll
    for (int ch = 0; ch < 4; ch++) {           // s chunks of 512
        for (int es = 0; es < 4; es++) {       // e slices of 16
            __syncthreads();
            // stage K[ch*512 .. +512)[es*16 .. +16) -> sK
            #pragma unroll
            for (int r = 0; r < 8; r++) {
                int p   = tid + 256 * r;       // float4 piece id, 2048 total
                int sl  = p >> 2;
                int col = p & 3;
                const float4 kv = *(const float4*)(Kg +
                    ((size_t)(ch * SCHUNK + sl) * H_DIM + h) * E_DIM
                    + es * ESLICE + col * 4);
                int slot = sl * 4 + ((col + ((sl >> 1) & 3)) & 3);  // XOR swizzle
                *(float4*)(sK + slot * 4) = kv;
            }
            __syncthreads();
            #pragma unroll
            for (int e4 = 0; e4 < 4; e4++) {
                float4 qf[4];
                #pragma unroll
                for (int jj = 0; jj < 4; jj++) {
                    int t = t0 + jj;
                    qf[jj] = *(const float4*)(Qg +
                        ((size_t)t * H_DIM + h) * E_DIM + es * ESLICE + e4 * 4);
                }
                #pragma unroll
                for (int i = 0; i < 8; i++) {
                    int sl   = lane + 64 * i;
                    int slot = sl * 4 + ((e4 + swz) & 3);
                    float4 kf = *(const float4*)(sK + slot * 4);
                    // e-sequential FMA chain (order matters for bit-match!)
                    #pragma unroll
                    for (int jj = 0; jj < 4; jj++) {
                        acc[jj][ch][i] = fmaf(qf[jj].x, kf.x, acc[jj][ch][i]);
                        acc[jj][ch][i] = fmaf(qf[jj].y, kf.y, acc[jj][ch][i]);
                        acc[jj][ch][i] = fmaf(qf[jj].z, kf.z, acc[jj][ch][i]);
                        acc[jj][ch][i] = fmaf(qf[jj].w, kf.w, acc[jj][ch][i]);
                    }
                }
            }
        }
    }

    __syncthreads();   // sK (K-tile) dead; selection scratch may now alias it

    // ---- selection + softmax + output (wave-local; per-wave scratch) ----
    const float* Vb = Vg + (size_t)h * E_DIM;

    #pragma unroll
    for (int jj = 0; jj < 4; jj++) {
        // --- adaptive radix: find exact threshold with <=64 candidates ---
        unsigned prefix = 0, count_above = 0, cnt_eq = 0;
        bool done = false;
        #pragma unroll
        for (int lvl = 0; lvl < 3; lvl++) {
            if (!done) {                       // wave-uniform condition
                const int shift = 22 - 10 * lvl;
                #pragma unroll
                for (int z = 0; z < 16; z++) histw[z * 64 + lane] = 0u;
                #pragma unroll
                for (int ch = 0; ch < 4; ch++)
                    #pragma unroll
                    for (int i = 0; i < 8; i++) {
                        unsigned u = f2ord(acc[jj][ch][i] * 0.125f);
                        bool part = (lvl == 0) ||
                                    ((u >> (shift + 10)) == (prefix >> (shift + 10)));
                        if (part)
                            atomicAdd(&histw[hmap((int)((u >> shift) & 1023u))], 1u);
                    }
                const unsigned need = K_TOP - count_above;   // >=1, wave-uniform
                unsigned seg = 0;
                const int btop = 1023 - 16 * lane;           // descending segments
                #pragma unroll
                for (int k = 0; k < 16; k++) seg += histw[hmap(btop - k)];
                unsigned inc = seg;
                #pragma unroll
                for (int d = 1; d < 64; d <<= 1) {
                    unsigned y = __shfl_up(inc, d);
                    if (lane >= d) inc += y;
                }
                unsigned pre = inc - seg;                    // count above my segment
                bool cross = (pre < need) && (pre + seg >= need);
                int bl = 0; unsigned cg = 0, ce = 0;
                if (cross) {
                    unsigned c = pre;
                    #pragma unroll
                    for (int k = 0; k < 16; k++) {
                        unsigned hb = histw[hmap(btop - k)];
                        if (c < need && c + hb >= need) { bl = btop - k; cg = c; ce = hb; }
                        c += hb;
                    }
                }
                int src = __ffsll((unsigned long long)__ballot(cross)) - 1;
                bl = __shfl(bl, src);
                cg = __shfl(cg, src);
                ce = __shfl(ce, src);
                prefix |= ((unsigned)bl) << shift;
                count_above += cg;             // stays < 32
                cnt_eq = ce;
                done = (count_above + cnt_eq <= 60u) || (lvl == 2);
            }
        }

        // --- collect candidates with u >= prefix (exact; same bits as radix) ---
        if (lane == 0) *wcntw = 0u;
        #pragma unroll
        for (int ch = 0; ch < 4; ch++)
            #pragma unroll
            for (int i = 0; i < 8; i++) {
                unsigned u = f2ord(acc[jj][ch][i] * 0.125f);
                if (u >= prefix) {
                    unsigned pos = atomicAdd(wcntw, 1u);
                    if (pos < 64u) {
                        candUw[pos] = u;
                        candIw[pos] = ch * SCHUNK + i * 64 + lane;
                    }
                }
            }
        unsigned n = *wcntw;                   // 32 <= n <= ~61 structurally
        if (n > 64u) n = 64u;

        // --- 64-wide bitonic, descending by (value, then lower index) ---
        unsigned long long key = 0ull;
        if ((unsigned)lane < n)
            key = (((unsigned long long)candUw[lane]) << 32)
                | (unsigned)(~candIw[lane]);
        #pragma unroll
        for (int k = 2; k <= 64; k <<= 1)
            #pragma unroll
            for (int j = k >> 1; j > 0; j >>= 1) {
                unsigned long long ok = __shfl_xor(key, j);
                bool takemax = ((lane & j) == 0) ^ ((lane & k) != 0);
                bool mineG   = key > ok;
                key = (takemax == mineG) ? key : ok;
            }

        // --- decode, softmax over lanes 0..31 (fp32 scores), V gather ---
        float val  = ord2f((unsigned)(key >> 32));
        int   sidx = (int)(~(unsigned)key);
        float m = __shfl(val, 0);              // lane 0 = max (n >= 32 always)
        float w = (lane < K_TOP) ? expf(val - m) : 0.f;
        float Z = w;
        #pragma unroll
        for (int d = 32; d > 0; d >>= 1) Z += __shfl_xor(Z, d);
        float p = w / Z;

        float o = 0.f;
        #pragma unroll
        for (int i2 = 0; i2 < K_TOP; i2++) {
            float pi = __shfl(p, i2);
            int   s2 = __shfl(sidx, i2);
            o = fmaf(pi, Vb[(size_t)s2 * (H_DIM * E_DIM) + lane], o);
        }
        int t = t0 + jj;
        Out[((size_t)t * H_DIM + h) * E_DIM + lane] = o;
    }
}

extern "C" void kernel_launch(void* const* d_in, const int* in_sizes, int n_in,
                              void* d_out, int out_size, void* d_ws, size_t ws_size,
                              hipStream_t stream) {
    const float* Q = (const float*)d_in[0];
    const float* K = (const float*)d_in[1];
    const float* V = (const float*)d_in[2];
    float* O = (float*)d_out;
    (void)in_sizes; (void)n_in; (void)out_size; (void)d_ws; (void)ws_size;
    dim3 grid((T_DIM / TT) * H_DIM);   // 2048 blocks
    dim3 block(256);
    topk_attn_kernel<<<grid, block, 0, stream>>>(Q, K, V, O);
}